// Round 2
// baseline (834.118 us; speedup 1.0000x reference)
//
#include <hip/hip_runtime.h>
#include <math.h>

typedef unsigned short u16;
typedef __bf16 bf16x8 __attribute__((ext_vector_type(8)));
typedef float f32x4 __attribute__((ext_vector_type(4)));

#define T_TOK 4096
#define DIMD 2048
#define HIDD 1024
#define NEXP 16
#define RMAX 12288
#define MAXBLK 96
#define BM 256
#define BN 128
#define BK 32

__device__ __forceinline__ u16 f2b(float f) {
  unsigned u = __builtin_bit_cast(unsigned, f);
  unsigned r = (u + 0x7FFFu + ((u >> 16) & 1u)) >> 16;  // RNE
  return (u16)r;
}

__device__ __forceinline__ void gld16(const void* g, void* l) {
  __builtin_amdgcn_global_load_lds(
      (const __attribute__((address_space(1))) void*)g,
      (__attribute__((address_space(3))) void*)l, 16, 0, 0);
}

// ---------------- small kernels ----------------

__global__ void k_zero(float* __restrict__ o) {
  const int i = blockIdx.x * blockDim.x + threadIdx.x;
  float4 z = {0.f, 0.f, 0.f, 0.f};
  ((float4*)o)[i] = z;
}

__global__ void k_init(int* perm, int* cnt, int* fill) {
  int i = blockIdx.x * blockDim.x + threadIdx.x;
  if (i < RMAX) perm[i] = -1;
  if (i < NEXP) { cnt[i] = 0; fill[i] = 0; }
}

__global__ void k_cvt(const float* __restrict__ x, u16* __restrict__ xb) {
  const int i = blockIdx.x * blockDim.x + threadIdx.x;
  const float4 v = ((const float4*)x)[i];
  union { u16 u[4]; unsigned long long q; } t;
  t.u[0] = f2b(v.x); t.u[1] = f2b(v.y); t.u[2] = f2b(v.z); t.u[3] = f2b(v.w);
  ((unsigned long long*)xb)[i] = t.q;
}

// transpose+convert: W fp32 [E][K][N] -> Wt bf16 rows of n: Wt[e-part][n][k]
__global__ __launch_bounds__(256)
void k_tr(const float* __restrict__ W, u16* __restrict__ Wt,
          int K, int N, long estride, int ld_out) {
  __shared__ float t[64][65];
  const int e = blockIdx.z;
  const float* Win = W + (size_t)e * (size_t)K * (size_t)N;
  u16* Wo = Wt + (size_t)e * (size_t)estride;
  const int n0 = blockIdx.x * 64, k0 = blockIdx.y * 64;
  const int r = threadIdx.x >> 4;
  const int c = (threadIdx.x & 15) * 4;
#pragma unroll
  for (int p = 0; p < 4; ++p) {
    const int kk = p * 16 + r;
    const float4 v = *(const float4*)&Win[(size_t)(k0 + kk) * N + n0 + c];
    t[kk][c] = v.x; t[kk][c + 1] = v.y; t[kk][c + 2] = v.z; t[kk][c + 3] = v.w;
  }
  __syncthreads();
#pragma unroll
  for (int p = 0; p < 4; ++p) {
    const int nn = p * 16 + r;
    ushort4 o;
    o.x = f2b(t[c + 0][nn]); o.y = f2b(t[c + 1][nn]);
    o.z = f2b(t[c + 2][nn]); o.w = f2b(t[c + 3][nn]);
    *(ushort4*)&Wo[(size_t)(n0 + nn) * ld_out + k0 + c] = o;
  }
}

// gating: fp32 logits = x @ gate_w, softmax, top-2, partial prob sums
__global__ __launch_bounds__(256)
void k_gate(const float* __restrict__ x, const float* __restrict__ gw,
            int* __restrict__ top2i, float* __restrict__ top2w,
            int* __restrict__ cnt, float* __restrict__ partial) {
  const int e = threadIdx.x & 15;
  const int tt = threadIdx.x >> 4;
  const int t = blockIdx.x * 16 + tt;
  const float* xp = x + (size_t)t * DIMD;
  float acc = 0.f;
#pragma unroll 8
  for (int k = 0; k < DIMD; ++k) acc = fmaf(xp[k], gw[k * NEXP + e], acc);
  __shared__ float lg[16][17];
  __shared__ float pr[16][17];
  lg[tt][e] = acc;
  __syncthreads();
  if (e == 0) {
    float l[16];
    float mx = -1e30f;
    for (int j = 0; j < 16; ++j) { l[j] = lg[tt][j]; mx = fmaxf(mx, l[j]); }
    float s = 0.f;
    for (int j = 0; j < 16; ++j) { l[j] = expf(l[j] - mx); s += l[j]; }
    const float inv = 1.f / s;
    float p1 = -1.f, p2 = -1.f; int i1 = 0, i2 = 0;
    for (int j = 0; j < 16; ++j) {
      const float p = l[j] * inv;
      pr[tt][j] = p;
      if (p > p1) { p2 = p1; i2 = i1; p1 = p; i1 = j; }
      else if (p > p2) { p2 = p; i2 = j; }
    }
    const float wsum = p1 + p2;
    top2i[t * 2 + 0] = i1;
    top2i[t * 2 + 1] = i2;
    top2w[t * 2 + 0] = p1 / wsum;
    top2w[t * 2 + 1] = p2 / wsum;
    atomicAdd(&cnt[i1], 1);
    atomicAdd(&cnt[i2], 1);
  }
  __syncthreads();
  if (tt == 0) {
    float s = 0.f;
    for (int j = 0; j < 16; ++j) s += pr[j][e];
    partial[blockIdx.x * 16 + e] = s;
  }
}

__global__ __launch_bounds__(256)
void k_aux(const float* __restrict__ partial, float* __restrict__ auxOut) {
  __shared__ float s[16][17];
  const int e = threadIdx.x & 15, c = threadIdx.x >> 4;
  float a = 0.f;
  for (int b = c; b < 256; b += 16) a += partial[b * 16 + e];
  s[c][e] = a;
  __syncthreads();
  if (threadIdx.x == 0) {
    float aux = 0.f;
    for (int j = 0; j < 16; ++j) {
      float tot = 0.f;
      for (int cc = 0; cc < 16; ++cc) tot += s[cc][j];
      const float m = tot / (float)T_TOK;
      aux += m * m;
    }
    auxOut[0] = aux * (float)NEXP;
  }
}

__global__ void k_off(const int* __restrict__ cnt, int* __restrict__ offs,
                      int* __restrict__ tbl_e, int* __restrict__ tbl_r0,
                      int* __restrict__ nblk) {
  if (threadIdx.x != 0 || blockIdx.x != 0) return;
  int o = 0, nb = 0;
  for (int e = 0; e < NEXP; ++e) {
    offs[e] = o;
    const int b = (cnt[e] + BM - 1) / BM;
    for (int i = 0; i < b; ++i) { tbl_e[nb] = e; tbl_r0[nb] = o + i * BM; ++nb; }
    o += b * BM;
  }
  offs[NEXP] = o;
  nblk[0] = nb;
}

__global__ void k_fill(const int* __restrict__ top2i, const float* __restrict__ top2w,
                       const int* __restrict__ offs, int* __restrict__ fill,
                       int* __restrict__ perm, float* __restrict__ wrow) {
  const int id = blockIdx.x * blockDim.x + threadIdx.x;
  if (id >= T_TOK * 2) return;
  const int e = top2i[id];
  const int pos = atomicAdd(&fill[e], 1);
  const int r = offs[e] + pos;
  perm[r] = id >> 1;
  wrow[r] = top2w[id];
}

// ---------------- GEMM core ----------------
// BM=256 x BN=128 tile, BK=32, 512 threads (8 waves, 4M x 2N).
// Double-buffered LDS, ONE barrier per K-step (T3 minimal 2-phase):
//   prologue stage buf0; loop { stage buf^1(t+1); ds_read+MFMA buf; barrier }.
// Per wave staging: A rows [16w,16w+16) and [128+16w,..); B rows [16w,16w+16).
__device__ __forceinline__ void gemm_body(
    const u16* __restrict__ ap0, const u16* __restrict__ ap1,
    const u16* __restrict__ bp0, int K,
    u16* __restrict__ As, u16* __restrict__ Bs,
    int w, int lane, f32x4 (&acc)[4][4]) {
  const int aoff_st = w * 16 * BK;            // wave-uniform LDS stage base (elems)
  const int boff_st = w * 16 * BK;
  const int wm = w >> 1, wn = w & 1;
  const int lm = lane & 15, lq = lane >> 4;
  const int aoff_rd = (wm * 64 + lm) * BK + lq * 8;
  const int boff_rd = (wn * 64 + lm) * BK + lq * 8;
  const int nst = K / BK;

  // prologue: stage tile 0 into buffer 0
  gld16(ap0, As + aoff_st);
  gld16(ap1, As + 128 * BK + aoff_st);
  gld16(bp0, Bs + boff_st);
  __syncthreads();  // compiler drains vmcnt(0) before s_barrier

  int cur = 0;
  for (int t = 1; t < nst; ++t) {
    // stage next tile into the other buffer (overlaps with compute below)
    const int k1 = t * BK;
    u16* dA = As + (cur ^ 1) * (BM * BK) + aoff_st;
    gld16(ap0 + k1, dA);
    gld16(ap1 + k1, dA + 128 * BK);
    gld16(bp0 + k1, Bs + (cur ^ 1) * (BN * BK) + boff_st);

    const u16* aR = As + cur * (BM * BK) + aoff_rd;
    const u16* bR = Bs + cur * (BN * BK) + boff_rd;
    bf16x8 af[4], bq[4];
#pragma unroll
    for (int i = 0; i < 4; ++i) af[i] = *(const bf16x8*)(aR + i * 16 * BK);
#pragma unroll
    for (int j = 0; j < 4; ++j) bq[j] = *(const bf16x8*)(bR + j * 16 * BK);
#pragma unroll
    for (int i = 0; i < 4; ++i)
#pragma unroll
      for (int j = 0; j < 4; ++j)
        acc[i][j] = __builtin_amdgcn_mfma_f32_16x16x32_bf16(af[i], bq[j], acc[i][j], 0, 0, 0);
    __syncthreads();  // next tile staged + all reads of cur done
    cur ^= 1;
  }
  // last tile: compute only
  {
    const u16* aR = As + cur * (BM * BK) + aoff_rd;
    const u16* bR = Bs + cur * (BN * BK) + boff_rd;
    bf16x8 af[4], bq[4];
#pragma unroll
    for (int i = 0; i < 4; ++i) af[i] = *(const bf16x8*)(aR + i * 16 * BK);
#pragma unroll
    for (int j = 0; j < 4; ++j) bq[j] = *(const bf16x8*)(bR + j * 16 * BK);
#pragma unroll
    for (int i = 0; i < 4; ++i)
#pragma unroll
      for (int j = 0; j < 4; ++j)
        acc[i][j] = __builtin_amdgcn_mfma_f32_16x16x32_bf16(af[i], bq[j], acc[i][j], 0, 0, 0);
  }
}

// Fused up-projection: shared experts (bx<32) + routed experts (bx>=32).
// K=2048 for all. N-tile by<8 (N=1024 per expert part).
__global__ __launch_bounds__(512, 4)
void k_up(const u16* __restrict__ xb, const u16* __restrict__ sw1t,
          const u16* __restrict__ w1t, u16* __restrict__ hbS,
          u16* __restrict__ hbR, const int* __restrict__ perm,
          const int* __restrict__ tbl_e, const int* __restrict__ tbl_r0,
          const int* __restrict__ nblk) {
  __shared__ u16 As[2 * BM * BK];  // 32 KB
  __shared__ u16 Bs[2 * BN * BK];  // 16 KB

  const int bx = blockIdx.x, by = blockIdx.y;
  const int tid = threadIdx.x;
  const int w = tid >> 6, lane = tid & 63;
  const int lr = lane >> 2;
  const int lk = (lane & 3) * 8;

  const bool routed = bx >= 32;
  int expert, r0, ga0, ga1;
  const u16* B;
  if (!routed) {
    expert = bx >> 4;                // shared-expert index
    r0 = (bx & 15) * BM;
    B = sw1t + (size_t)expert * (size_t)HIDD * DIMD;
    ga0 = r0 + w * 16 + lr;
    ga1 = r0 + 128 + w * 16 + lr;
  } else {
    const int rbx = bx - 32;
    if (rbx >= *nblk) return;
    expert = tbl_e[rbx];
    r0 = tbl_r0[rbx];
    B = w1t + (size_t)expert * (size_t)HIDD * DIMD;
    const int p0 = perm[r0 + w * 16 + lr];       ga0 = (p0 < 0) ? 0 : p0;
    const int p1 = perm[r0 + 128 + w * 16 + lr]; ga1 = (p1 < 0) ? 0 : p1;
  }

  const int n0 = by * BN;
  const u16* ap0 = xb + (size_t)ga0 * DIMD + lk;
  const u16* ap1 = xb + (size_t)ga1 * DIMD + lk;
  const u16* bp0 = B + (size_t)(n0 + w * 16 + lr) * DIMD + lk;

  f32x4 acc[4][4];
#pragma unroll
  for (int i = 0; i < 4; ++i)
#pragma unroll
    for (int j = 0; j < 4; ++j) {
      acc[i][j][0] = 0.f; acc[i][j][1] = 0.f; acc[i][j][2] = 0.f; acc[i][j][3] = 0.f;
    }

  gemm_body(ap0, ap1, bp0, DIMD, As, Bs, w, lane, acc);

  const int wm = w >> 1, wn = w & 1;
  const int lm = lane & 15, lq = lane >> 4;
#pragma unroll
  for (int i = 0; i < 4; ++i) {
#pragma unroll
    for (int r = 0; r < 4; ++r) {
      const int row = r0 + wm * 64 + i * 16 + lq * 4 + r;
      u16* dst = routed ? &hbR[(size_t)row * HIDD]
                        : &hbS[(size_t)row * DIMD + expert * HIDD];
#pragma unroll
      for (int j = 0; j < 4; ++j) {
        const int gc = n0 + wn * 64 + j * 16 + lm;
        const float v = acc[i][j][r];
        const float s = v / (1.f + expf(-v));
        dst[gc] = f2b(s);
      }
    }
  }
}

// Fused down-projection: shared (bx<16, K=2048 concat) + routed (bx>=16, K=1024).
// out pre-zeroed; all accumulation via atomicAdd. by<16 (N=2048).
__global__ __launch_bounds__(512, 4)
void k_down(const u16* __restrict__ hbS, const u16* __restrict__ hbR,
            const u16* __restrict__ sw2ct, const u16* __restrict__ w2t,
            float* __restrict__ out, const int* __restrict__ perm,
            const float* __restrict__ wrow,
            const int* __restrict__ tbl_e, const int* __restrict__ tbl_r0,
            const int* __restrict__ nblk) {
  __shared__ u16 As[2 * BM * BK];
  __shared__ u16 Bs[2 * BN * BK];

  const int bx = blockIdx.x, by = blockIdx.y;
  const int tid = threadIdx.x;
  const int w = tid >> 6, lane = tid & 63;
  const int lr = lane >> 2;
  const int lk = (lane & 3) * 8;

  const bool routed = bx >= 16;
  int r0, K, ld;
  const u16 *Amat, *B;
  if (!routed) {
    r0 = bx * BM;
    Amat = hbS; K = DIMD; ld = DIMD;
    B = sw2ct;
  } else {
    const int rbx = bx - 16;
    if (rbx >= *nblk) return;
    const int expert = tbl_e[rbx];
    r0 = tbl_r0[rbx];
    Amat = hbR; K = HIDD; ld = HIDD;
    B = w2t + (size_t)expert * (size_t)DIMD * HIDD;
  }

  const int n0 = by * BN;
  const u16* ap0 = Amat + (size_t)(r0 + w * 16 + lr) * ld + lk;
  const u16* ap1 = Amat + (size_t)(r0 + 128 + w * 16 + lr) * ld + lk;
  const u16* bp0 = B + (size_t)(n0 + w * 16 + lr) * ld + lk;

  f32x4 acc[4][4];
#pragma unroll
  for (int i = 0; i < 4; ++i)
#pragma unroll
    for (int j = 0; j < 4; ++j) {
      acc[i][j][0] = 0.f; acc[i][j][1] = 0.f; acc[i][j][2] = 0.f; acc[i][j][3] = 0.f;
    }

  gemm_body(ap0, ap1, bp0, K, As, Bs, w, lane, acc);

  const int wm = w >> 1, wn = w & 1;
  const int lm = lane & 15, lq = lane >> 4;
#pragma unroll
  for (int i = 0; i < 4; ++i) {
#pragma unroll
    for (int r = 0; r < 4; ++r) {
      const int rr = r0 + wm * 64 + i * 16 + lq * 4 + r;
      int t; float wt;
      if (!routed) { t = rr; wt = 1.f; }
      else { t = perm[rr]; wt = (t >= 0) ? wrow[rr] : 0.f; }
      if (t >= 0) {
        float* dst = &out[(size_t)t * DIMD];
#pragma unroll
        for (int j = 0; j < 4; ++j) {
          const int gc = n0 + wn * 64 + j * 16 + lm;
          atomicAdd(&dst[gc], wt * acc[i][j][r]);
        }
      }
    }
  }
}

// ---------------- launch ----------------

extern "C" void kernel_launch(void* const* d_in, const int* in_sizes, int n_in,
                              void* d_out, int out_size, void* d_ws, size_t ws_size,
                              hipStream_t stream) {
  const float* x   = (const float*)d_in[0];
  const float* gw  = (const float*)d_in[1];
  const float* sw1 = (const float*)d_in[2];
  const float* sw2 = (const float*)d_in[3];
  const float* w1  = (const float*)d_in[4];
  const float* w2  = (const float*)d_in[5];
  float* out = (float*)d_out;

  char* ws = (char*)d_ws;
  u16* xb    = (u16*)(ws);                         // 16 MB
  u16* hbS   = (u16*)(ws + (size_t)( 16 << 20));   // 16 MB
  u16* hbR   = (u16*)(ws + (size_t)( 32 << 20));   // 24 MB  [12288][1024]
  u16* sw1t  = (u16*)(ws + (size_t)( 56 << 20));   //  8 MB  [2][1024][2048]
  u16* sw2ct = (u16*)(ws + (size_t)( 64 << 20));   //  8 MB  [2048][2*1024] concat
  u16* w1t   = (u16*)(ws + (size_t)( 72 << 20));   // 64 MB  [16][1024][2048]
  u16* w2t   = (u16*)(ws + (size_t)(136 << 20));   // 64 MB  [16][2048][1024]
  char* p = ws + (size_t)(200 << 20);
  int*   top2i   = (int*)p;    p += T_TOK * 2 * 4;
  float* top2w   = (float*)p;  p += T_TOK * 2 * 4;
  int*   perm    = (int*)p;    p += RMAX * 4;
  float* wrow    = (float*)p;  p += RMAX * 4;
  int*   cnt     = (int*)p;    p += 16 * 4;
  int*   fill    = (int*)p;    p += 16 * 4;
  int*   offs    = (int*)p;    p += 32 * 4;
  int*   tbl_e   = (int*)p;    p += MAXBLK * 4;
  int*   tbl_r0  = (int*)p;    p += MAXBLK * 4;
  int*   nblk    = (int*)p;    p += 16 * 4;
  float* partial = (float*)p;  p += 256 * 16 * 4;

  // out must be zero before k_down's atomic accumulation
  k_zero<<<(T_TOK * DIMD / 4) / 256, 256, 0, stream>>>(out);
  k_init<<<(RMAX + 255) / 256, 256, 0, stream>>>(perm, cnt, fill);
  k_cvt<<<(T_TOK * DIMD / 4) / 256, 256, 0, stream>>>(x, xb);
  k_gate<<<T_TOK / 16, 256, 0, stream>>>(x, gw, top2i, top2w, cnt, partial);
  k_off<<<1, 64, 0, stream>>>(cnt, offs, tbl_e, tbl_r0, nblk);
  k_fill<<<(T_TOK * 2 + 255) / 256, 256, 0, stream>>>(top2i, top2w, offs, fill, perm, wrow);
  k_aux<<<1, 256, 0, stream>>>(partial, out + (size_t)T_TOK * DIMD);

  // weight transposes (fp32 [K][N] -> bf16 [n][k])
  k_tr<<<dim3(1024 / 64, 2048 / 64,  2), 256, 0, stream>>>(sw1, sw1t, 2048, 1024, 1024l * 2048, 2048);
  k_tr<<<dim3(2048 / 64, 1024 / 64,  2), 256, 0, stream>>>(sw2, sw2ct, 1024, 2048, 1024, 2048);
  k_tr<<<dim3(1024 / 64, 2048 / 64, 16), 256, 0, stream>>>(w1, w1t, 2048, 1024, 1024l * 2048, 2048);
  k_tr<<<dim3(2048 / 64, 1024 / 64, 16), 256, 0, stream>>>(w2, w2t, 1024, 2048, 2048l * 1024, 1024);

  // fused up-projection: 32 shared blocks (2 experts x 16 row-tiles) + <=48 routed
  k_up<<<dim3(32 + 48, 8), 512, 0, stream>>>(xb, sw1t, w1t, hbS, hbR,
                                             perm, tbl_e, tbl_r0, nblk);
  // fused down-projection: 16 shared blocks + <=48 routed, 16 col-tiles
  k_down<<<dim3(16 + 48, 16), 512, 0, stream>>>(hbS, hbR, sw2ct, w2t, out,
                                                perm, wrow, tbl_e, tbl_r0, nblk);
}

// Round 3
// 813.411 us; speedup vs baseline: 1.0255x; 1.0255x over previous
//
#include <hip/hip_runtime.h>
#include <math.h>

typedef unsigned short u16;
typedef __bf16 bf16x8 __attribute__((ext_vector_type(8)));
typedef float f32x4 __attribute__((ext_vector_type(4)));

#define T_TOK 4096
#define DIMD 2048
#define HIDD 1024
#define NEXP 16
#define RMAX 10240
#define MAXBLK 96
#define BM 128
#define BN 256
#define BK 64

__device__ __forceinline__ u16 f2b(float f) {
  unsigned u = __builtin_bit_cast(unsigned, f);
  unsigned r = (u + 0x7FFFu + ((u >> 16) & 1u)) >> 16;  // RNE
  return (u16)r;
}

__device__ __forceinline__ void gld16(const void* g, void* l) {
  __builtin_amdgcn_global_load_lds(
      (const __attribute__((address_space(1))) void*)g,
      (__attribute__((address_space(3))) void*)l, 16, 0, 0);
}

// ---------------- small kernels ----------------

__global__ void k_zero(float* __restrict__ o) {
  const int i = blockIdx.x * blockDim.x + threadIdx.x;
  float4 z = {0.f, 0.f, 0.f, 0.f};
  ((float4*)o)[i] = z;
}

__global__ void k_init(int* perm, int* cnt, int* fill) {
  int i = blockIdx.x * blockDim.x + threadIdx.x;
  if (i < RMAX) perm[i] = -1;
  if (i < NEXP) { cnt[i] = 0; fill[i] = 0; }
}

__global__ void k_cvt(const float* __restrict__ x, u16* __restrict__ xb) {
  const int i = blockIdx.x * blockDim.x + threadIdx.x;
  const float4 v = ((const float4*)x)[i];
  union { u16 u[4]; unsigned long long q; } t;
  t.u[0] = f2b(v.x); t.u[1] = f2b(v.y); t.u[2] = f2b(v.z); t.u[3] = f2b(v.w);
  ((unsigned long long*)xb)[i] = t.q;
}

// transpose+convert: W fp32 [E][K][N] -> Wt bf16 rows of n: Wt[e-part][n][k]
__global__ __launch_bounds__(256)
void k_tr(const float* __restrict__ W, u16* __restrict__ Wt,
          int K, int N, long estride, int ld_out) {
  __shared__ float t[64][65];
  const int e = blockIdx.z;
  const float* Win = W + (size_t)e * (size_t)K * (size_t)N;
  u16* Wo = Wt + (size_t)e * (size_t)estride;
  const int n0 = blockIdx.x * 64, k0 = blockIdx.y * 64;
  const int r = threadIdx.x >> 4;
  const int c = (threadIdx.x & 15) * 4;
#pragma unroll
  for (int p = 0; p < 4; ++p) {
    const int kk = p * 16 + r;
    const float4 v = *(const float4*)&Win[(size_t)(k0 + kk) * N + n0 + c];
    t[kk][c] = v.x; t[kk][c + 1] = v.y; t[kk][c + 2] = v.z; t[kk][c + 3] = v.w;
  }
  __syncthreads();
#pragma unroll
  for (int p = 0; p < 4; ++p) {
    const int nn = p * 16 + r;
    ushort4 o;
    o.x = f2b(t[c + 0][nn]); o.y = f2b(t[c + 1][nn]);
    o.z = f2b(t[c + 2][nn]); o.w = f2b(t[c + 3][nn]);
    *(ushort4*)&Wo[(size_t)(n0 + nn) * ld_out + k0 + c] = o;
  }
}

// gating: fp32 logits = x @ gate_w, softmax, top-2, partial prob sums
__global__ __launch_bounds__(256)
void k_gate(const float* __restrict__ x, const float* __restrict__ gw,
            int* __restrict__ top2i, float* __restrict__ top2w,
            int* __restrict__ cnt, float* __restrict__ partial) {
  const int e = threadIdx.x & 15;
  const int tt = threadIdx.x >> 4;
  const int t = blockIdx.x * 16 + tt;
  const float* xp = x + (size_t)t * DIMD;
  float acc = 0.f;
#pragma unroll 8
  for (int k = 0; k < DIMD; ++k) acc = fmaf(xp[k], gw[k * NEXP + e], acc);
  __shared__ float lg[16][17];
  __shared__ float pr[16][17];
  lg[tt][e] = acc;
  __syncthreads();
  if (e == 0) {
    float l[16];
    float mx = -1e30f;
    for (int j = 0; j < 16; ++j) { l[j] = lg[tt][j]; mx = fmaxf(mx, l[j]); }
    float s = 0.f;
    for (int j = 0; j < 16; ++j) { l[j] = expf(l[j] - mx); s += l[j]; }
    const float inv = 1.f / s;
    float p1 = -1.f, p2 = -1.f; int i1 = 0, i2 = 0;
    for (int j = 0; j < 16; ++j) {
      const float p = l[j] * inv;
      pr[tt][j] = p;
      if (p > p1) { p2 = p1; i2 = i1; p1 = p; i1 = j; }
      else if (p > p2) { p2 = p; i2 = j; }
    }
    const float wsum = p1 + p2;
    top2i[t * 2 + 0] = i1;
    top2i[t * 2 + 1] = i2;
    top2w[t * 2 + 0] = p1 / wsum;
    top2w[t * 2 + 1] = p2 / wsum;
    atomicAdd(&cnt[i1], 1);
    atomicAdd(&cnt[i2], 1);
  }
  __syncthreads();
  if (tt == 0) {
    float s = 0.f;
    for (int j = 0; j < 16; ++j) s += pr[j][e];
    partial[blockIdx.x * 16 + e] = s;
  }
}

__global__ __launch_bounds__(256)
void k_aux(const float* __restrict__ partial, float* __restrict__ auxOut) {
  __shared__ float s[16][17];
  const int e = threadIdx.x & 15, c = threadIdx.x >> 4;
  float a = 0.f;
  for (int b = c; b < 256; b += 16) a += partial[b * 16 + e];
  s[c][e] = a;
  __syncthreads();
  if (threadIdx.x == 0) {
    float aux = 0.f;
    for (int j = 0; j < 16; ++j) {
      float tot = 0.f;
      for (int cc = 0; cc < 16; ++cc) tot += s[cc][j];
      const float m = tot / (float)T_TOK;
      aux += m * m;
    }
    auxOut[0] = aux * (float)NEXP;
  }
}

__global__ void k_off(const int* __restrict__ cnt, int* __restrict__ offs,
                      int* __restrict__ tbl_e, int* __restrict__ tbl_r0,
                      int* __restrict__ nblk) {
  if (threadIdx.x != 0 || blockIdx.x != 0) return;
  int o = 0, nb = 0;
  for (int e = 0; e < NEXP; ++e) {
    offs[e] = o;
    const int b = (cnt[e] + BM - 1) / BM;
    for (int i = 0; i < b; ++i) { tbl_e[nb] = e; tbl_r0[nb] = o + i * BM; ++nb; }
    o += b * BM;
  }
  offs[NEXP] = o;
  nblk[0] = nb;
}

__global__ void k_fill(const int* __restrict__ top2i, const float* __restrict__ top2w,
                       const int* __restrict__ offs, int* __restrict__ fill,
                       int* __restrict__ perm, float* __restrict__ wrow) {
  const int id = blockIdx.x * blockDim.x + threadIdx.x;
  if (id >= T_TOK * 2) return;
  const int e = top2i[id];
  const int pos = atomicAdd(&fill[e], 1);
  const int r = offs[e] + pos;
  perm[r] = id >> 1;
  wrow[r] = top2w[id];
}

// ---------------- GEMM core: counted-vmcnt ring-2 pipeline ----------------
// Tile BM=128 x BN=256, BK=64. 512 threads = 8 waves (2M x 4N), 64x64 C/wave.
// LDS per buffer: A [128][64] (16KB) + B [256][64] (32KB); ring of 2 = 96KB.
// Swizzle: LDS slot (row, chunk c) holds global chunk c ^ ((row>>1)&7)
// (chunk = 16B = 8 bf16). Applied on the GLOBAL source per lane (linear LDS
// dest for global_load_lds), and on the ds_read address. Makes the 16-row
// fragment reads conflict-free (2 lanes/bank-group).
// Schedule per K-tile: compute(buf) ; s_barrier ; stage(t+2 -> buf) ;
// s_waitcnt vmcnt(6) ; s_barrier.  Prefetch loads stay in flight across
// barriers (T3/T4); no vmcnt(0) drain in the main loop.

__device__ __forceinline__ void stage_tile(
    const u16* gA0, const u16* gA1, const u16* gB0, const u16* gB1,
    const u16* gB2, const u16* gB3, int k0, u16* S, int b, int w) {
  u16* As = S + b * 24576;
  u16* Bs = As + 8192;
  gld16(gA0 + k0, As + w * 512);
  gld16(gA1 + k0, As + 4096 + w * 512);
  gld16(gB0 + k0, Bs + w * 512);
  gld16(gB1 + k0, Bs + 4096 + w * 512);
  gld16(gB2 + k0, Bs + 8192 + w * 512);
  gld16(gB3 + k0, Bs + 12288 + w * 512);
}

__device__ __forceinline__ void comp_tile(const u16* __restrict__ S, int b,
    const int (&aoff)[4][2], const int (&boff)[4][2], f32x4 (&acc)[4][4]) {
  const u16* As = S + b * 24576;
  const u16* Bs = As + 8192;
#pragma unroll
  for (int kh = 0; kh < 2; ++kh) {
    bf16x8 a[4], bq[4];
#pragma unroll
    for (int i = 0; i < 4; ++i) a[i] = *(const bf16x8*)(As + aoff[i][kh]);
#pragma unroll
    for (int j = 0; j < 4; ++j) bq[j] = *(const bf16x8*)(Bs + boff[j][kh]);
    __builtin_amdgcn_s_setprio(1);
#pragma unroll
    for (int i = 0; i < 4; ++i)
#pragma unroll
      for (int j = 0; j < 4; ++j)
        acc[i][j] = __builtin_amdgcn_mfma_f32_16x16x32_bf16(a[i], bq[j], acc[i][j], 0, 0, 0);
    __builtin_amdgcn_s_setprio(0);
  }
}

#define FENCE asm volatile("" ::: "memory")
#define VMW6  asm volatile("s_waitcnt vmcnt(6)" ::: "memory")
#define VMW0  asm volatile("s_waitcnt vmcnt(0)" ::: "memory")

__device__ __forceinline__ void gemm_pipe(
    const u16* gA0, const u16* gA1, const u16* gB0, const u16* gB1,
    const u16* gB2, const u16* gB3, int K, u16* S,
    const int (&aoff)[4][2], const int (&boff)[4][2],
    f32x4 (&acc)[4][4], int w) {
  const int nt = K >> 6;  // even (16 or 32)
  stage_tile(gA0, gA1, gB0, gB1, gB2, gB3, 0, S, 0, w);
  stage_tile(gA0, gA1, gB0, gB1, gB2, gB3, 64, S, 1, w);
  VMW6;                              // tile0 landed (tile1's 6 in flight)
  __builtin_amdgcn_s_barrier();
  FENCE;
  for (int t = 0; t < nt - 2; ++t) {
    comp_tile(S, t & 1, aoff, boff, acc);
    FENCE;
    __builtin_amdgcn_s_barrier();    // all waves done reading buf (t&1)
    FENCE;
    stage_tile(gA0, gA1, gB0, gB1, gB2, gB3, (t + 2) << 6, S, t & 1, w);
    VMW6;                            // tile t+1 landed; t+2's 6 in flight
    __builtin_amdgcn_s_barrier();
    FENCE;
  }
  comp_tile(S, 0, aoff, boff, acc);  // tile nt-2 ((nt-2)&1 == 0)
  VMW0;                              // tile nt-1 landed
  __builtin_amdgcn_s_barrier();
  FENCE;
  comp_tile(S, 1, aoff, boff, acc);  // tile nt-1
}

// Fused up-projection. Shared (bx<32): concat-N B = sw1t [2048n][2048k],
// out hbS [4096][2048]. Routed (bx>=32, by<4): per-expert B, out hbR.
// K=2048, lda=ldb=2048 for all.
__global__ __launch_bounds__(512, 2)
void k_up(const u16* __restrict__ xb, const u16* __restrict__ sw1t,
          const u16* __restrict__ w1t, u16* __restrict__ hbS,
          u16* __restrict__ hbR, const int* __restrict__ perm,
          const int* __restrict__ tbl_e, const int* __restrict__ tbl_r0,
          const int* __restrict__ nblk) {
  __shared__ u16 S[49152];  // 96 KB
  const int bx = blockIdx.x, by = blockIdx.y;
  const int tid = threadIdx.x;
  const int w = tid >> 6, lane = tid & 63;
  const int lm = lane & 15, lq = lane >> 4;
  const int wm = w >> 2, wn = w & 3;
  const int srow = w * 8 + (lane >> 3);  // 0..63 staging row within a pass
  const int c8 = lane & 7;               // 16B chunk within a 64-elem row

  const bool routed = bx >= 32;
  int r0, ga0, ga1;
  const u16* Bb;
  if (!routed) {
    r0 = bx * BM;
    Bb = sw1t;
    ga0 = r0 + srow; ga1 = r0 + 64 + srow;
  } else {
    if (by >= 4) return;
    const int rbx = bx - 32;
    if (rbx >= *nblk) return;
    const int e = tbl_e[rbx];
    r0 = tbl_r0[rbx];
    Bb = w1t + (size_t)e * (size_t)HIDD * DIMD;
    const int p0 = perm[r0 + srow];      ga0 = (p0 < 0) ? 0 : p0;
    const int p1 = perm[r0 + 64 + srow]; ga1 = (p1 < 0) ? 0 : p1;
  }
  const int n0 = by * BN;
  // pre-swizzled global sources (linear LDS dest => swizzle on source)
  const u16* gA0 = xb + (size_t)ga0 * DIMD + (c8 ^ ((srow >> 1) & 7)) * 8;
  const u16* gA1 = xb + (size_t)ga1 * DIMD + (c8 ^ (((64 + srow) >> 1) & 7)) * 8;
  const u16* gB[4];
#pragma unroll
  for (int p = 0; p < 4; ++p) {
    const int n = p * 64 + srow;
    gB[p] = Bb + (size_t)(n0 + n) * DIMD + (c8 ^ ((n >> 1) & 7)) * 8;
  }
  int aoff[4][2], boff[4][2];
#pragma unroll
  for (int i = 0; i < 4; ++i) {
    const int m = wm * 64 + i * 16 + lm;
    const int n = wn * 64 + i * 16 + lm;
#pragma unroll
    for (int kh = 0; kh < 2; ++kh) {
      aoff[i][kh] = m * 64 + (((kh << 2) | lq) ^ ((m >> 1) & 7)) * 8;
      boff[i][kh] = n * 64 + (((kh << 2) | lq) ^ ((n >> 1) & 7)) * 8;
    }
  }
  f32x4 acc[4][4];
#pragma unroll
  for (int i = 0; i < 4; ++i)
#pragma unroll
    for (int j = 0; j < 4; ++j) {
      acc[i][j][0] = 0.f; acc[i][j][1] = 0.f; acc[i][j][2] = 0.f; acc[i][j][3] = 0.f;
    }

  gemm_pipe(gA0, gA1, gB[0], gB[1], gB[2], gB[3], DIMD, S, aoff, boff, acc, w);

#pragma unroll
  for (int i = 0; i < 4; ++i) {
#pragma unroll
    for (int r = 0; r < 4; ++r) {
      const int row = r0 + wm * 64 + i * 16 + lq * 4 + r;
      u16* dst = routed ? &hbR[(size_t)row * HIDD] : &hbS[(size_t)row * DIMD];
#pragma unroll
      for (int j = 0; j < 4; ++j) {
        const int gc = n0 + wn * 64 + j * 16 + lm;
        const float v = acc[i][j][r];
        const float s = v / (1.f + expf(-v));
        dst[gc] = f2b(s);
      }
    }
  }
}

// Fused down-projection: shared (bx<32, A=hbS K=2048) + routed (bx>=32,
// A=hbR K=1024). N=2048 (by<8). out pre-zeroed; atomicAdd accumulation.
__global__ __launch_bounds__(512, 2)
void k_down(const u16* __restrict__ hbS, const u16* __restrict__ hbR,
            const u16* __restrict__ sw2ct, const u16* __restrict__ w2t,
            float* __restrict__ out, const int* __restrict__ perm,
            const float* __restrict__ wrow,
            const int* __restrict__ tbl_e, const int* __restrict__ tbl_r0,
            const int* __restrict__ nblk) {
  __shared__ u16 S[49152];
  const int bx = blockIdx.x, by = blockIdx.y;
  const int tid = threadIdx.x;
  const int w = tid >> 6, lane = tid & 63;
  const int lm = lane & 15, lq = lane >> 4;
  const int wm = w >> 2, wn = w & 3;
  const int srow = w * 8 + (lane >> 3);
  const int c8 = lane & 7;

  const bool routed = bx >= 32;
  int r0, K, ld;
  const u16 *Ab, *Bb;
  if (!routed) {
    r0 = bx * BM;
    Ab = hbS; K = DIMD; ld = DIMD;
    Bb = sw2ct;
  } else {
    const int rbx = bx - 32;
    if (rbx >= *nblk) return;
    const int e = tbl_e[rbx];
    r0 = tbl_r0[rbx];
    Ab = hbR; K = HIDD; ld = HIDD;
    Bb = w2t + (size_t)e * (size_t)DIMD * HIDD;
  }
  const int n0 = by * BN;
  const u16* gA0 = Ab + (size_t)(r0 + srow) * ld + (c8 ^ ((srow >> 1) & 7)) * 8;
  const u16* gA1 = Ab + (size_t)(r0 + 64 + srow) * ld + (c8 ^ (((64 + srow) >> 1) & 7)) * 8;
  const u16* gB[4];
#pragma unroll
  for (int p = 0; p < 4; ++p) {
    const int n = p * 64 + srow;
    gB[p] = Bb + (size_t)(n0 + n) * ld + (c8 ^ ((n >> 1) & 7)) * 8;
  }
  int aoff[4][2], boff[4][2];
#pragma unroll
  for (int i = 0; i < 4; ++i) {
    const int m = wm * 64 + i * 16 + lm;
    const int n = wn * 64 + i * 16 + lm;
#pragma unroll
    for (int kh = 0; kh < 2; ++kh) {
      aoff[i][kh] = m * 64 + (((kh << 2) | lq) ^ ((m >> 1) & 7)) * 8;
      boff[i][kh] = n * 64 + (((kh << 2) | lq) ^ ((n >> 1) & 7)) * 8;
    }
  }
  f32x4 acc[4][4];
#pragma unroll
  for (int i = 0; i < 4; ++i)
#pragma unroll
    for (int j = 0; j < 4; ++j) {
      acc[i][j][0] = 0.f; acc[i][j][1] = 0.f; acc[i][j][2] = 0.f; acc[i][j][3] = 0.f;
    }

  gemm_pipe(gA0, gA1, gB[0], gB[1], gB[2], gB[3], K, S, aoff, boff, acc, w);

#pragma unroll
  for (int i = 0; i < 4; ++i) {
#pragma unroll
    for (int r = 0; r < 4; ++r) {
      const int rr = r0 + wm * 64 + i * 16 + lq * 4 + r;
      int t; float wt;
      if (!routed) { t = rr; wt = 1.f; }
      else { t = perm[rr]; wt = (t >= 0) ? wrow[rr] : 0.f; }
      if (t >= 0) {
        float* dst = &out[(size_t)t * DIMD];
#pragma unroll
        for (int j = 0; j < 4; ++j) {
          const int gc = n0 + wn * 64 + j * 16 + lm;
          atomicAdd(&dst[gc], wt * acc[i][j][r]);
        }
      }
    }
  }
}

// ---------------- launch ----------------

extern "C" void kernel_launch(void* const* d_in, const int* in_sizes, int n_in,
                              void* d_out, int out_size, void* d_ws, size_t ws_size,
                              hipStream_t stream) {
  const float* x   = (const float*)d_in[0];
  const float* gw  = (const float*)d_in[1];
  const float* sw1 = (const float*)d_in[2];
  const float* sw2 = (const float*)d_in[3];
  const float* w1  = (const float*)d_in[4];
  const float* w2  = (const float*)d_in[5];
  float* out = (float*)d_out;

  char* ws = (char*)d_ws;
  u16* xb    = (u16*)(ws);                         // 16 MB
  u16* hbS   = (u16*)(ws + (size_t)( 16 << 20));   // 16 MB  [4096][2048]
  u16* hbR   = (u16*)(ws + (size_t)( 32 << 20));   // 20 MB  [10240][1024]
  u16* sw1t  = (u16*)(ws + (size_t)( 56 << 20));   //  8 MB  [2][1024][2048] (concat n)
  u16* sw2ct = (u16*)(ws + (size_t)( 64 << 20));   //  8 MB  [2048][2*1024] concat k
  u16* w1t   = (u16*)(ws + (size_t)( 72 << 20));   // 64 MB  [16][1024][2048]
  u16* w2t   = (u16*)(ws + (size_t)(136 << 20));   // 64 MB  [16][2048][1024]
  char* p = ws + (size_t)(200 << 20);
  int*   top2i   = (int*)p;    p += T_TOK * 2 * 4;
  float* top2w   = (float*)p;  p += T_TOK * 2 * 4;
  int*   perm    = (int*)p;    p += RMAX * 4;
  float* wrow    = (float*)p;  p += RMAX * 4;
  int*   cnt     = (int*)p;    p += 16 * 4;
  int*   fill    = (int*)p;    p += 16 * 4;
  int*   offs    = (int*)p;    p += 32 * 4;
  int*   tbl_e   = (int*)p;    p += MAXBLK * 4;
  int*   tbl_r0  = (int*)p;    p += MAXBLK * 4;
  int*   nblk    = (int*)p;    p += 16 * 4;
  float* partial = (float*)p;  p += 256 * 16 * 4;

  // out must be zero before k_down's atomic accumulation
  k_zero<<<(T_TOK * DIMD / 4) / 256, 256, 0, stream>>>(out);
  k_init<<<(RMAX + 255) / 256, 256, 0, stream>>>(perm, cnt, fill);
  k_cvt<<<(T_TOK * DIMD / 4) / 256, 256, 0, stream>>>(x, xb);
  k_gate<<<T_TOK / 16, 256, 0, stream>>>(x, gw, top2i, top2w, cnt, partial);
  k_off<<<1, 64, 0, stream>>>(cnt, offs, tbl_e, tbl_r0, nblk);
  k_fill<<<(T_TOK * 2 + 255) / 256, 256, 0, stream>>>(top2i, top2w, offs, fill, perm, wrow);
  k_aux<<<1, 256, 0, stream>>>(partial, out + (size_t)T_TOK * DIMD);

  // weight transposes (fp32 [K][N] -> bf16 [n][k])
  k_tr<<<dim3(1024 / 64, 2048 / 64,  2), 256, 0, stream>>>(sw1, sw1t, 2048, 1024, 1024l * 2048, 2048);
  k_tr<<<dim3(2048 / 64, 1024 / 64,  2), 256, 0, stream>>>(sw2, sw2ct, 1024, 2048, 1024, 2048);
  k_tr<<<dim3(1024 / 64, 2048 / 64, 16), 256, 0, stream>>>(w1, w1t, 2048, 1024, 1024l * 2048, 2048);
  k_tr<<<dim3(2048 / 64, 1024 / 64, 16), 256, 0, stream>>>(w2, w2t, 1024, 2048, 2048l * 1024, 1024);

  // fused up-projection: shared 32 row-blocks x 8 n-tiles (concat N=2048) +
  // routed <=96 row-blocks x 4 n-tiles (N=1024)
  k_up<<<dim3(32 + MAXBLK, 8), 512, 0, stream>>>(xb, sw1t, w1t, hbS, hbR,
                                                 perm, tbl_e, tbl_r0, nblk);
  // fused down-projection: shared 32 + routed <=96 row-blocks, 8 n-tiles
  k_down<<<dim3(32 + MAXBLK, 8), 512, 0, stream>>>(hbS, hbR, sw2ct, w2t, out,
                                                   perm, wrow, tbl_e, tbl_r0, nblk);
}